// Round 1
// baseline (1010.321 us; speedup 1.0000x reference)
//
#include <hip/hip_runtime.h>
#include <cstdint>
#include <cstddef>

#define N_NODES 50000
#define N_EDGES 1600000
#define D 512
#define MPAD 50048   // 391 * 128, padded M for 128-row GEMM tiles

typedef __attribute__((ext_vector_type(8))) short bf16x8;
typedef __attribute__((ext_vector_type(4))) float f32x4;
typedef __attribute__((ext_vector_type(8))) unsigned short u16x8;

static __device__ __forceinline__ unsigned short f2bf(float f) {
  unsigned u = __float_as_uint(f);
  u += 0x7fffu + ((u >> 16) & 1u);   // RNE
  return (unsigned short)(u >> 16);
}

// ---------------- convert x (f32 -> bf16, zero-pad rows to MPAD) ----------------
__global__ __launch_bounds__(256) void convert_x(const float* __restrict__ x,
                                                 unsigned short* __restrict__ xb) {
  size_t i = ((size_t)blockIdx.x * 256 + threadIdx.x) * 8;
  if (i >= (size_t)MPAD * D) return;
  u16x8 v;
  if (i < (size_t)N_NODES * D) {           // N_NODES*D divisible by 8: no straddle
    const float4* f = (const float4*)(x + i);
    float4 f0 = f[0], f1 = f[1];
    v[0] = f2bf(f0.x); v[1] = f2bf(f0.y); v[2] = f2bf(f0.z); v[3] = f2bf(f0.w);
    v[4] = f2bf(f1.x); v[5] = f2bf(f1.y); v[6] = f2bf(f1.z); v[7] = f2bf(f1.w);
  } else {
    v = (u16x8)(unsigned short)0;
  }
  *(u16x8*)(xb + i) = v;
}

// ---------------- convert w0,w1 -> transposed bf16 W^T[1024][512] ----------------
// wbT[n][k] = (n<512 ? w0[k][n] : w1[k][n-512])
__global__ __launch_bounds__(256) void convert_w(const float* __restrict__ w0,
                                                 const float* __restrict__ w1,
                                                 unsigned short* __restrict__ wbT) {
  int idx = blockIdx.x * 256 + threadIdx.x;
  if (idx >= 1024 * D) return;
  int n = idx & 1023;
  int k = idx >> 10;
  float v = (n < 512) ? w0[k * 512 + n] : w1[k * 512 + (n - 512)];
  wbT[n * D + k] = f2bf(v);
}

// ---------------- histogram of destination rows ----------------
__global__ __launch_bounds__(256) void histogram(const int* __restrict__ r0,
                                                 const int* __restrict__ r1,
                                                 int* __restrict__ c0,
                                                 int* __restrict__ c1) {
  int stride = gridDim.x * blockDim.x;
  for (int i = blockIdx.x * blockDim.x + threadIdx.x; i < 2 * N_EDGES; i += stride) {
    if (i < N_EDGES) atomicAdd(&c0[r0[i]], 1);
    else             atomicAdd(&c1[r1[i - N_EDGES]], 1);
  }
}

// ---------------- exclusive scan (one block per support) ----------------
__global__ __launch_bounds__(1024) void scan2(const int* __restrict__ cnt0,
                                              const int* __restrict__ cnt1,
                                              int* __restrict__ rp0, int* __restrict__ rp1,
                                              int* __restrict__ cur0, int* __restrict__ cur1) {
  __shared__ int tmp[1024];
  const int* cnt = (blockIdx.x == 0) ? cnt0 : cnt1;
  int* rp  = (blockIdx.x == 0) ? rp0  : rp1;
  int* cur = (blockIdx.x == 0) ? cur0 : cur1;
  const int t = threadIdx.x;
  int carry = 0;
  for (int base = 0; base < N_NODES; base += 1024) {
    int idx = base + t;
    int c = (idx < N_NODES) ? cnt[idx] : 0;
    tmp[t] = c;
    __syncthreads();
    for (int off = 1; off < 1024; off <<= 1) {
      int v = (t >= off) ? tmp[t - off] : 0;
      __syncthreads();
      tmp[t] += v;
      __syncthreads();
    }
    int inc = tmp[t];
    int tot = tmp[1023];
    if (idx < N_NODES) {
      int ex = carry + inc - c;
      rp[idx] = ex;
      cur[idx] = ex;
    }
    __syncthreads();   // protect tmp before next iteration overwrites
    carry += tot;
  }
  if (t == 0) rp[N_NODES] = carry;
}

// ---------------- CSR fill (atomic cursors) ----------------
__global__ __launch_bounds__(256) void fill_csr(const int* __restrict__ r0, const int* __restrict__ co0, const float* __restrict__ v0,
                                                const int* __restrict__ r1, const int* __restrict__ co1, const float* __restrict__ v1,
                                                int* __restrict__ cur0, int* __restrict__ cur1,
                                                int* __restrict__ ec0, float* __restrict__ ev0,
                                                int* __restrict__ ec1, float* __restrict__ ev1) {
  int stride = gridDim.x * blockDim.x;
  for (int i = blockIdx.x * blockDim.x + threadIdx.x; i < 2 * N_EDGES; i += stride) {
    if (i < N_EDGES) {
      int p = atomicAdd(&cur0[r0[i]], 1);
      ec0[p] = co0[i];
      ev0[p] = v0[i];
    } else {
      int j = i - N_EDGES;
      int p = atomicAdd(&cur1[r1[j]], 1);
      ec1[p] = co1[j];
      ev1[p] = v1[j];
    }
  }
}

// ---------------- GEMM: pre[MPAD][1024] bf16 = xb[MPAD][512] @ W[512][1024] ----------------
// m97 structure: 128x128 tile, BK=32, 4 waves each 64x64 (4x4 frags of 16x16x32 MFMA)
#define BM 128
#define BN 128
#define BK 32

__global__ __launch_bounds__(256) void gemm_pre(const unsigned short* __restrict__ xb,
                                                const unsigned short* __restrict__ wbT,
                                                unsigned short* __restrict__ pre) {
  __shared__ __align__(16) unsigned short As[BM * BK];
  __shared__ __align__(16) unsigned short Bs[BN * BK];
  const int t = threadIdx.x;
  const int lane = t & 63;
  const int wave = t >> 6;
  const int wm = wave >> 1, wn = wave & 1;
  const int lr = lane & 15;
  const int lk = (lane >> 4) * 8;
  const int m0 = blockIdx.y * BM;
  const int n0 = blockIdx.x * BN;

  f32x4 acc[4][4] = {};

  for (int kt = 0; kt < D / BK; ++kt) {
    #pragma unroll
    for (int i = 0; i < 2; ++i) {
      int ch = i * 256 + t;          // 16B chunk index, 512 per tile
      int row = ch >> 2;             // 4 chunks per 32-elem row
      int ke = (ch & 3) * 8;
      const unsigned short* ga = xb + (size_t)(m0 + row) * D + kt * BK + ke;
      __builtin_amdgcn_global_load_lds(
          (const __attribute__((address_space(1))) unsigned int*)ga,
          (__attribute__((address_space(3))) unsigned int*)(&As[ch * 8]), 16, 0, 0);
      const unsigned short* gb = wbT + (size_t)(n0 + row) * D + kt * BK + ke;
      __builtin_amdgcn_global_load_lds(
          (const __attribute__((address_space(1))) unsigned int*)gb,
          (__attribute__((address_space(3))) unsigned int*)(&Bs[ch * 8]), 16, 0, 0);
    }
    __syncthreads();

    bf16x8 a[4], b[4];
    #pragma unroll
    for (int i = 0; i < 4; ++i)
      a[i] = *(const bf16x8*)&As[(wm * 64 + i * 16 + lr) * BK + lk];
    #pragma unroll
    for (int j = 0; j < 4; ++j)
      b[j] = *(const bf16x8*)&Bs[(wn * 64 + j * 16 + lr) * BK + lk];
    #pragma unroll
    for (int i = 0; i < 4; ++i)
      #pragma unroll
      for (int j = 0; j < 4; ++j)
        acc[i][j] = __builtin_amdgcn_mfma_f32_16x16x32_bf16(a[i], b[j], acc[i][j], 0, 0, 0);
    __syncthreads();
  }

  // store: C/D layout col = lane&15, row = (lane>>4)*4 + reg
  const int orow = (lane >> 4) * 4;
  #pragma unroll
  for (int i = 0; i < 4; ++i) {
    #pragma unroll
    for (int j = 0; j < 4; ++j) {
      #pragma unroll
      for (int r = 0; r < 4; ++r) {
        int row = m0 + wm * 64 + i * 16 + orow + r;
        int col = n0 + wn * 64 + j * 16 + lr;
        pre[(size_t)row * 1024 + col] = f2bf(acc[i][j][r]);
      }
    }
  }
}

// ---------------- SpMM gather + bias + ReLU ----------------
// One block per output node; thread t owns cols 2t, 2t+1.
__global__ __launch_bounds__(256) void spmm_out(const unsigned short* __restrict__ pre,
    const int* __restrict__ rp0, const int* __restrict__ ec0, const float* __restrict__ ev0,
    const int* __restrict__ rp1, const int* __restrict__ ec1, const float* __restrict__ ev1,
    const float* __restrict__ bias, float* __restrict__ out) {
  const int n = blockIdx.x;
  const int t = threadIdx.x;
  float a0 = 0.f, a1 = 0.f;

  // support 0: cols [0,512) of pre
  {
    const int beg = rp0[n], end = rp0[n + 1];
    int p = beg;
    for (; p + 4 <= end; p += 4) {
      int   cA = ec0[p],     cB = ec0[p + 1], cC = ec0[p + 2], cD = ec0[p + 3];
      float vA = ev0[p],     vB = ev0[p + 1], vC = ev0[p + 2], vD = ev0[p + 3];
      unsigned uA = *(const unsigned*)(pre + (size_t)cA * 1024 + 2 * t);
      unsigned uB = *(const unsigned*)(pre + (size_t)cB * 1024 + 2 * t);
      unsigned uC = *(const unsigned*)(pre + (size_t)cC * 1024 + 2 * t);
      unsigned uD = *(const unsigned*)(pre + (size_t)cD * 1024 + 2 * t);
      a0 += vA * __uint_as_float(uA << 16);  a1 += vA * __uint_as_float(uA & 0xffff0000u);
      a0 += vB * __uint_as_float(uB << 16);  a1 += vB * __uint_as_float(uB & 0xffff0000u);
      a0 += vC * __uint_as_float(uC << 16);  a1 += vC * __uint_as_float(uC & 0xffff0000u);
      a0 += vD * __uint_as_float(uD << 16);  a1 += vD * __uint_as_float(uD & 0xffff0000u);
    }
    for (; p < end; ++p) {
      int c = ec0[p]; float v = ev0[p];
      unsigned u = *(const unsigned*)(pre + (size_t)c * 1024 + 2 * t);
      a0 += v * __uint_as_float(u << 16);  a1 += v * __uint_as_float(u & 0xffff0000u);
    }
  }
  // support 1: cols [512,1024) of pre
  {
    const int beg = rp1[n], end = rp1[n + 1];
    int p = beg;
    for (; p + 4 <= end; p += 4) {
      int   cA = ec1[p],     cB = ec1[p + 1], cC = ec1[p + 2], cD = ec1[p + 3];
      float vA = ev1[p],     vB = ev1[p + 1], vC = ev1[p + 2], vD = ev1[p + 3];
      unsigned uA = *(const unsigned*)(pre + (size_t)cA * 1024 + 512 + 2 * t);
      unsigned uB = *(const unsigned*)(pre + (size_t)cB * 1024 + 512 + 2 * t);
      unsigned uC = *(const unsigned*)(pre + (size_t)cC * 1024 + 512 + 2 * t);
      unsigned uD = *(const unsigned*)(pre + (size_t)cD * 1024 + 512 + 2 * t);
      a0 += vA * __uint_as_float(uA << 16);  a1 += vA * __uint_as_float(uA & 0xffff0000u);
      a0 += vB * __uint_as_float(uB << 16);  a1 += vB * __uint_as_float(uB & 0xffff0000u);
      a0 += vC * __uint_as_float(uC << 16);  a1 += vC * __uint_as_float(uC & 0xffff0000u);
      a0 += vD * __uint_as_float(uD << 16);  a1 += vD * __uint_as_float(uD & 0xffff0000u);
    }
    for (; p < end; ++p) {
      int c = ec1[p]; float v = ev1[p];
      unsigned u = *(const unsigned*)(pre + (size_t)c * 1024 + 512 + 2 * t);
      a0 += v * __uint_as_float(u << 16);  a1 += v * __uint_as_float(u & 0xffff0000u);
    }
  }

  float2 o;
  o.x = fmaxf(a0 + bias[2 * t], 0.f);
  o.y = fmaxf(a1 + bias[2 * t + 1], 0.f);
  *(float2*)(out + (size_t)n * 512 + 2 * t) = o;
}

// ---------------- launch ----------------
extern "C" void kernel_launch(void* const* d_in, const int* in_sizes, int n_in,
                              void* d_out, int out_size, void* d_ws, size_t ws_size,
                              hipStream_t stream) {
  const float* x     = (const float*)d_in[0];
  const float* w0    = (const float*)d_in[1];
  const float* w1    = (const float*)d_in[2];
  const float* bias  = (const float*)d_in[3];
  const float* vals0 = (const float*)d_in[4];
  const float* vals1 = (const float*)d_in[5];
  const int*   rows0 = (const int*)d_in[6];
  const int*   cols0 = (const int*)d_in[7];
  const int*   rows1 = (const int*)d_in[8];
  const int*   cols1 = (const int*)d_in[9];
  float* out = (float*)d_out;

  char* ws = (char*)d_ws;
  size_t off = 0;
  auto alloc = [&](size_t bytes) -> char* {
    char* p = ws + off;
    off += (bytes + 255) & ~(size_t)255;
    return p;
  };
  unsigned short* xb  = (unsigned short*)alloc((size_t)MPAD * D * 2);     // 51.2 MB
  unsigned short* wbT = (unsigned short*)alloc((size_t)1024 * D * 2);     // 1 MB
  unsigned short* pre = (unsigned short*)alloc((size_t)MPAD * 1024 * 2);  // 102.5 MB
  int* rp0  = (int*)alloc((N_NODES + 1) * sizeof(int));
  int* rp1  = (int*)alloc((N_NODES + 1) * sizeof(int));
  int* cur0 = (int*)alloc(N_NODES * sizeof(int));
  int* cur1 = (int*)alloc(N_NODES * sizeof(int));
  int* cnt  = (int*)alloc(2 * N_NODES * sizeof(int));  // cnt0 = cnt, cnt1 = cnt+N
  int*   ec0 = (int*)alloc(N_EDGES * sizeof(int));
  float* ev0 = (float*)alloc(N_EDGES * sizeof(float));
  int*   ec1 = (int*)alloc(N_EDGES * sizeof(int));
  float* ev1 = (float*)alloc(N_EDGES * sizeof(float));

  hipMemsetAsync(cnt, 0, 2 * N_NODES * sizeof(int), stream);

  convert_x<<<dim3((unsigned)((size_t)MPAD * D / 8 / 256)), 256, 0, stream>>>(x, xb);
  convert_w<<<dim3((1024 * D + 255) / 256), 256, 0, stream>>>(w0, w1, wbT);
  histogram<<<2048, 256, 0, stream>>>(rows0, rows1, cnt, cnt + N_NODES);
  scan2<<<2, 1024, 0, stream>>>(cnt, cnt + N_NODES, rp0, rp1, cur0, cur1);
  fill_csr<<<2048, 256, 0, stream>>>(rows0, cols0, vals0, rows1, cols1, vals1,
                                     cur0, cur1, ec0, ev0, ec1, ev1);
  gemm_pre<<<dim3(1024 / BN, MPAD / BM), 256, 0, stream>>>(xb, wbT, pre);
  spmm_out<<<N_NODES, 256, 0, stream>>>(pre, rp0, ec0, ev0, rp1, ec1, ev1, bias, out);
}

// Round 2
// 977.299 us; speedup vs baseline: 1.0338x; 1.0338x over previous
//
#include <hip/hip_runtime.h>
#include <cstdint>
#include <cstddef>

#define N_NODES 50000
#define N_EDGES 1600000
#define D 512
#define MPAD 50048   // 391 * 128, padded M for 128-row GEMM tiles

typedef __attribute__((ext_vector_type(8))) short bf16x8;
typedef __attribute__((ext_vector_type(4))) float f32x4;
typedef __attribute__((ext_vector_type(8))) unsigned short u16x8;

static __device__ __forceinline__ unsigned short f2bf(float f) {
  unsigned u = __float_as_uint(f);
  u += 0x7fffu + ((u >> 16) & 1u);   // RNE
  return (unsigned short)(u >> 16);
}

// ---------------- convert x (f32 -> bf16) ----------------
__global__ __launch_bounds__(256) void convert_x(const float* __restrict__ x,
                                                 unsigned short* __restrict__ xb) {
  size_t i = ((size_t)blockIdx.x * 256 + threadIdx.x) * 8;
  if (i >= (size_t)N_NODES * D) return;
  const float4* f = (const float4*)(x + i);
  float4 f0 = f[0], f1 = f[1];
  u16x8 v;
  v[0] = f2bf(f0.x); v[1] = f2bf(f0.y); v[2] = f2bf(f0.z); v[3] = f2bf(f0.w);
  v[4] = f2bf(f1.x); v[5] = f2bf(f1.y); v[6] = f2bf(f1.z); v[7] = f2bf(f1.w);
  *(u16x8*)(xb + i) = v;
}

// ---------------- convert w0,w1 -> wbT[512][1024]: wbT[j][k] = Wcat[k][j] ----------------
// Wcat[k][j] = (k<512 ? w0[k][j] : w1[k-512][j])
__global__ __launch_bounds__(256) void convert_w(const float* __restrict__ w0,
                                                 const float* __restrict__ w1,
                                                 unsigned short* __restrict__ wbT) {
  int idx = blockIdx.x * 256 + threadIdx.x;   // idx = j*1024 + k
  if (idx >= 512 * 1024) return;
  int k = idx & 1023;
  int j = idx >> 10;
  float v = (k < 512) ? w0[k * 512 + j] : w1[(k - 512) * 512 + j];
  wbT[idx] = f2bf(v);
}

// ---------------- histogram of destination rows (int4 reads) ----------------
__global__ __launch_bounds__(256) void histogram(const int* __restrict__ r0,
                                                 const int* __restrict__ r1,
                                                 int* __restrict__ c0,
                                                 int* __restrict__ c1) {
  const int nq = N_EDGES / 4;   // 400000 int4 per support
  int stride = gridDim.x * blockDim.x;
  for (int i = blockIdx.x * blockDim.x + threadIdx.x; i < 2 * nq; i += stride) {
    if (i < nq) {
      int4 r = ((const int4*)r0)[i];
      atomicAdd(&c0[r.x], 1); atomicAdd(&c0[r.y], 1);
      atomicAdd(&c0[r.z], 1); atomicAdd(&c0[r.w], 1);
    } else {
      int4 r = ((const int4*)r1)[i - nq];
      atomicAdd(&c1[r.x], 1); atomicAdd(&c1[r.y], 1);
      atomicAdd(&c1[r.z], 1); atomicAdd(&c1[r.w], 1);
    }
  }
}

// ---------------- exclusive scan, shuffle-based (one block per support) ----------------
__global__ __launch_bounds__(1024) void scan2(const int* __restrict__ cnt0,
                                              const int* __restrict__ cnt1,
                                              int* __restrict__ rp0, int* __restrict__ rp1,
                                              int* __restrict__ cur0, int* __restrict__ cur1) {
  __shared__ int wsum[16];
  __shared__ int stot;
  const int* cnt = (blockIdx.x == 0) ? cnt0 : cnt1;
  int* rp  = (blockIdx.x == 0) ? rp0  : rp1;
  int* cur = (blockIdx.x == 0) ? cur0 : cur1;
  const int t = threadIdx.x;
  const int lane = t & 63;
  const int wave = t >> 6;
  int carry = 0;
  for (int base = 0; base < N_NODES; base += 4096) {
    int idx = base + t * 4;
    int c0 = 0, c1 = 0, c2 = 0, c3 = 0;
    if (idx + 3 < N_NODES) {
      int4 c = *(const int4*)(cnt + idx);
      c0 = c.x; c1 = c.y; c2 = c.z; c3 = c.w;
    } else {
      if (idx     < N_NODES) c0 = cnt[idx];
      if (idx + 1 < N_NODES) c1 = cnt[idx + 1];
      if (idx + 2 < N_NODES) c2 = cnt[idx + 2];
      if (idx + 3 < N_NODES) c3 = cnt[idx + 3];
    }
    int s0 = c0, s01 = s0 + c1, s012 = s01 + c2, tsum = s012 + c3;
    // wave-inclusive scan of tsum
    int incl = tsum;
    #pragma unroll
    for (int off = 1; off < 64; off <<= 1) {
      int v = __shfl_up(incl, off, 64);
      if (lane >= off) incl += v;
    }
    if (lane == 63) wsum[wave] = incl;
    __syncthreads();
    if (wave == 0) {
      int v = (lane < 16) ? wsum[lane] : 0;
      int winc = v;
      #pragma unroll
      for (int off = 1; off < 16; off <<= 1) {
        int u = __shfl_up(winc, off, 64);
        if (lane >= off) winc += u;
      }
      if (lane < 16) wsum[lane] = winc - v;   // exclusive
      if (lane == 15) stot = winc;            // chunk total
    }
    __syncthreads();
    int ebase = carry + wsum[wave] + (incl - tsum);
    if (idx     < N_NODES) { rp[idx]     = ebase;        cur[idx]     = ebase; }
    if (idx + 1 < N_NODES) { rp[idx + 1] = ebase + s0;   cur[idx + 1] = ebase + s0; }
    if (idx + 2 < N_NODES) { rp[idx + 2] = ebase + s01;  cur[idx + 2] = ebase + s01; }
    if (idx + 3 < N_NODES) { rp[idx + 3] = ebase + s012; cur[idx + 3] = ebase + s012; }
    carry += stot;
    __syncthreads();   // protect wsum/stot before next chunk
  }
  if (t == 0) rp[N_NODES] = carry;
}

// ---------------- CSR fill: packed (col, val) int2 ----------------
__global__ __launch_bounds__(256) void fill_csr(const int* __restrict__ r0, const int* __restrict__ co0, const float* __restrict__ v0,
                                                const int* __restrict__ r1, const int* __restrict__ co1, const float* __restrict__ v1,
                                                int* __restrict__ cur0, int* __restrict__ cur1,
                                                int2* __restrict__ e0, int2* __restrict__ e1) {
  int stride = gridDim.x * blockDim.x;
  for (int i = blockIdx.x * blockDim.x + threadIdx.x; i < 2 * N_EDGES; i += stride) {
    if (i < N_EDGES) {
      int p = atomicAdd(&cur0[r0[i]], 1);
      e0[p] = make_int2(co0[i], __float_as_int(v0[i]));
    } else {
      int j = i - N_EDGES;
      int p = atomicAdd(&cur1[r1[j]], 1);
      e1[p] = make_int2(co1[j], __float_as_int(v1[j]));
    }
  }
}

// ---------------- SpMM on x: s[n][0:512] = A0 xb, s[n][512:1024] = A1 xb ----------------
// Block = 4 waves; each wave gathers whole 512-col rows (8 cols/lane), waves split edges.
__global__ __launch_bounds__(256) void spmm_s(const unsigned short* __restrict__ xb,
    const int* __restrict__ rp0, const int2* __restrict__ e0,
    const int* __restrict__ rp1, const int2* __restrict__ e1,
    unsigned short* __restrict__ s) {
  __shared__ float red[4][512];
  const int n = blockIdx.x;
  const int t = threadIdx.x;
  const int lane = t & 63;
  const int wave = __builtin_amdgcn_readfirstlane(t >> 6);
  const int c0 = lane * 8;

  float a0[8] = {}, a1[8] = {};

  // support 0
  {
    const int beg = rp0[n], end = rp0[n + 1];
    int p = beg + wave;
    for (; p + 4 < end; p += 8) {
      int2 eA = e0[p], eB = e0[p + 4];
      u16x8 rA = *(const u16x8*)(xb + (size_t)eA.x * D + c0);
      u16x8 rB = *(const u16x8*)(xb + (size_t)eB.x * D + c0);
      float vA = __int_as_float(eA.y), vB = __int_as_float(eB.y);
      #pragma unroll
      for (int i = 0; i < 8; ++i) {
        a0[i] += vA * __uint_as_float(((unsigned)rA[i]) << 16);
        a0[i] += vB * __uint_as_float(((unsigned)rB[i]) << 16);
      }
    }
    if (p < end) {
      int2 eA = e0[p];
      u16x8 rA = *(const u16x8*)(xb + (size_t)eA.x * D + c0);
      float vA = __int_as_float(eA.y);
      #pragma unroll
      for (int i = 0; i < 8; ++i)
        a0[i] += vA * __uint_as_float(((unsigned)rA[i]) << 16);
    }
  }
  // support 1
  {
    const int beg = rp1[n], end = rp1[n + 1];
    int p = beg + wave;
    for (; p + 4 < end; p += 8) {
      int2 eA = e1[p], eB = e1[p + 4];
      u16x8 rA = *(const u16x8*)(xb + (size_t)eA.x * D + c0);
      u16x8 rB = *(const u16x8*)(xb + (size_t)eB.x * D + c0);
      float vA = __int_as_float(eA.y), vB = __int_as_float(eB.y);
      #pragma unroll
      for (int i = 0; i < 8; ++i) {
        a1[i] += vA * __uint_as_float(((unsigned)rA[i]) << 16);
        a1[i] += vB * __uint_as_float(((unsigned)rB[i]) << 16);
      }
    }
    if (p < end) {
      int2 eA = e1[p];
      u16x8 rA = *(const u16x8*)(xb + (size_t)eA.x * D + c0);
      float vA = __int_as_float(eA.y);
      #pragma unroll
      for (int i = 0; i < 8; ++i)
        a1[i] += vA * __uint_as_float(((unsigned)rA[i]) << 16);
    }
  }

  // reduce across waves, write bf16 s row
  #pragma unroll
  for (int i = 0; i < 8; ++i) red[wave][c0 + i] = a0[i];
  __syncthreads();
  {
    int cc = 2 * t;
    float x0 = red[0][cc] + red[1][cc] + red[2][cc] + red[3][cc];
    float x1 = red[0][cc + 1] + red[1][cc + 1] + red[2][cc + 1] + red[3][cc + 1];
    unsigned u = (unsigned)f2bf(x0) | ((unsigned)f2bf(x1) << 16);
    *(unsigned*)(s + (size_t)n * 1024 + cc) = u;
  }
  __syncthreads();
  #pragma unroll
  for (int i = 0; i < 8; ++i) red[wave][c0 + i] = a1[i];
  __syncthreads();
  {
    int cc = 2 * t;
    float x0 = red[0][cc] + red[1][cc] + red[2][cc] + red[3][cc];
    float x1 = red[0][cc + 1] + red[1][cc + 1] + red[2][cc + 1] + red[3][cc + 1];
    unsigned u = (unsigned)f2bf(x0) | ((unsigned)f2bf(x1) << 16);
    *(unsigned*)(s + (size_t)n * 1024 + 512 + cc) = u;
  }
}

// ---------------- GEMM: out[50000][512] = relu( s[MPAD][1024] @ Wcat[1024][512] + b ) ----------------
#define BM 128
#define BN 128
#define BK 32

__global__ __launch_bounds__(256) void gemm_out(const unsigned short* __restrict__ s,
                                                const unsigned short* __restrict__ wbT,
                                                const float* __restrict__ bias,
                                                float* __restrict__ out) {
  __shared__ __align__(16) unsigned short As[BM * BK];
  __shared__ __align__(16) unsigned short Bs[BN * BK];
  const int t = threadIdx.x;
  const int lane = t & 63;
  const int wave = t >> 6;
  const int wm = wave >> 1, wn = wave & 1;
  const int lr = lane & 15;
  const int lk = (lane >> 4) * 8;
  const int m0 = blockIdx.y * BM;
  const int n0 = blockIdx.x * BN;

  f32x4 acc[4][4] = {};

  for (int kt = 0; kt < 1024 / BK; ++kt) {
    #pragma unroll
    for (int i = 0; i < 2; ++i) {
      int ch = i * 256 + t;          // 16B chunk index, 512 per tile
      int row = ch >> 2;             // 4 chunks per 32-elem row
      int ke = (ch & 3) * 8;
      const unsigned short* ga = s + (size_t)(m0 + row) * 1024 + kt * BK + ke;
      __builtin_amdgcn_global_load_lds(
          (const __attribute__((address_space(1))) unsigned int*)ga,
          (__attribute__((address_space(3))) unsigned int*)(&As[ch * 8]), 16, 0, 0);
      const unsigned short* gb = wbT + (size_t)(n0 + row) * 1024 + kt * BK + ke;
      __builtin_amdgcn_global_load_lds(
          (const __attribute__((address_space(1))) unsigned int*)gb,
          (__attribute__((address_space(3))) unsigned int*)(&Bs[ch * 8]), 16, 0, 0);
    }
    __syncthreads();

    bf16x8 a[4], b[4];
    #pragma unroll
    for (int i = 0; i < 4; ++i)
      a[i] = *(const bf16x8*)&As[(wm * 64 + i * 16 + lr) * BK + lk];
    #pragma unroll
    for (int j = 0; j < 4; ++j)
      b[j] = *(const bf16x8*)&Bs[(wn * 64 + j * 16 + lr) * BK + lk];
    #pragma unroll
    for (int i = 0; i < 4; ++i)
      #pragma unroll
      for (int j = 0; j < 4; ++j)
        acc[i][j] = __builtin_amdgcn_mfma_f32_16x16x32_bf16(a[i], b[j], acc[i][j], 0, 0, 0);
    __syncthreads();
  }

  float bj[4];
  #pragma unroll
  for (int j = 0; j < 4; ++j) bj[j] = bias[n0 + wn * 64 + j * 16 + lr];

  const int orow = (lane >> 4) * 4;
  #pragma unroll
  for (int i = 0; i < 4; ++i) {
    #pragma unroll
    for (int j = 0; j < 4; ++j) {
      #pragma unroll
      for (int r = 0; r < 4; ++r) {
        int row = m0 + wm * 64 + i * 16 + orow + r;
        if (row < N_NODES) {
          int col = n0 + wn * 64 + j * 16 + lr;
          out[(size_t)row * 512 + col] = fmaxf(acc[i][j][r] + bj[j], 0.f);
        }
      }
    }
  }
}

// ---------------- launch ----------------
extern "C" void kernel_launch(void* const* d_in, const int* in_sizes, int n_in,
                              void* d_out, int out_size, void* d_ws, size_t ws_size,
                              hipStream_t stream) {
  const float* x     = (const float*)d_in[0];
  const float* w0    = (const float*)d_in[1];
  const float* w1    = (const float*)d_in[2];
  const float* bias  = (const float*)d_in[3];
  const float* vals0 = (const float*)d_in[4];
  const float* vals1 = (const float*)d_in[5];
  const int*   rows0 = (const int*)d_in[6];
  const int*   cols0 = (const int*)d_in[7];
  const int*   rows1 = (const int*)d_in[8];
  const int*   cols1 = (const int*)d_in[9];
  float* out = (float*)d_out;

  char* ws = (char*)d_ws;
  size_t off = 0;
  auto alloc = [&](size_t bytes) -> char* {
    char* p = ws + off;
    off += (bytes + 255) & ~(size_t)255;
    return p;
  };
  unsigned short* xb  = (unsigned short*)alloc((size_t)N_NODES * D * 2);   // 51.2 MB
  unsigned short* wbT = (unsigned short*)alloc((size_t)512 * 1024 * 2);    // 1 MB
  unsigned short* s   = (unsigned short*)alloc((size_t)MPAD * 1024 * 2);   // 102.5 MB
  int* rp0  = (int*)alloc((N_NODES + 1) * sizeof(int));
  int* rp1  = (int*)alloc((N_NODES + 1) * sizeof(int));
  int* cur0 = (int*)alloc(N_NODES * sizeof(int));
  int* cur1 = (int*)alloc(N_NODES * sizeof(int));
  int* cnt  = (int*)alloc(2 * N_NODES * sizeof(int));
  int2* e0  = (int2*)alloc((size_t)N_EDGES * sizeof(int2));                // 12.8 MB
  int2* e1  = (int2*)alloc((size_t)N_EDGES * sizeof(int2));                // 12.8 MB

  hipMemsetAsync(cnt, 0, 2 * N_NODES * sizeof(int), stream);
  // zero GEMM pad rows of s (rows 50000..50047)
  hipMemsetAsync(s + (size_t)N_NODES * 1024, 0, (size_t)(MPAD - N_NODES) * 1024 * 2, stream);

  convert_x<<<dim3((unsigned)((size_t)N_NODES * D / 8 / 256)), 256, 0, stream>>>(x, xb);
  convert_w<<<dim3(512 * 1024 / 256), 256, 0, stream>>>(w0, w1, wbT);
  histogram<<<2048, 256, 0, stream>>>(rows0, rows1, cnt, cnt + N_NODES);
  scan2<<<2, 1024, 0, stream>>>(cnt, cnt + N_NODES, rp0, rp1, cur0, cur1);
  fill_csr<<<2048, 256, 0, stream>>>(rows0, cols0, vals0, rows1, cols1, vals1,
                                     cur0, cur1, e0, e1);
  spmm_s<<<N_NODES, 256, 0, stream>>>(xb, rp0, e0, rp1, e1, s);
  gemm_out<<<dim3(512 / BN, MPAD / BM), 256, 0, stream>>>(s, wbT, bias, out);
}

// Round 3
// 959.767 us; speedup vs baseline: 1.0527x; 1.0183x over previous
//
#include <hip/hip_runtime.h>
#include <cstdint>
#include <cstddef>

#define N_NODES 50000
#define N_EDGES 1600000
#define D 512
#define MPAD 50048   // 391 * 128, padded M for 128-row GEMM tiles

typedef __attribute__((ext_vector_type(8))) short bf16x8;
typedef __attribute__((ext_vector_type(4))) float f32x4;
typedef __attribute__((ext_vector_type(8))) unsigned short u16x8;
typedef __attribute__((ext_vector_type(2))) int i32x2;
typedef __attribute__((ext_vector_type(4))) int i32x4;

static __device__ __forceinline__ unsigned short f2bf(float f) {
  unsigned u = __float_as_uint(f);
  u += 0x7fffu + ((u >> 16) & 1u);   // RNE
  return (unsigned short)(u >> 16);
}

// ---------------- convert x (f32 -> bf16); NT loads keep x out of L3 ----------------
__global__ __launch_bounds__(256) void convert_x(const float* __restrict__ x,
                                                 unsigned short* __restrict__ xb) {
  size_t i = ((size_t)blockIdx.x * 256 + threadIdx.x) * 8;
  if (i >= (size_t)N_NODES * D) return;
  const f32x4* f = (const f32x4*)(x + i);
  f32x4 f0 = __builtin_nontemporal_load(f);
  f32x4 f1 = __builtin_nontemporal_load(f + 1);
  u16x8 v;
  v[0] = f2bf(f0[0]); v[1] = f2bf(f0[1]); v[2] = f2bf(f0[2]); v[3] = f2bf(f0[3]);
  v[4] = f2bf(f1[0]); v[5] = f2bf(f1[1]); v[6] = f2bf(f1[2]); v[7] = f2bf(f1[3]);
  *(u16x8*)(xb + i) = v;    // cached: we WANT xb resident in L3
}

// ---------------- convert w0,w1 -> wbT[512][1024]: wbT[j][k] = Wcat[k][j] ----------------
__global__ __launch_bounds__(256) void convert_w(const float* __restrict__ w0,
                                                 const float* __restrict__ w1,
                                                 unsigned short* __restrict__ wbT) {
  int idx = blockIdx.x * 256 + threadIdx.x;   // idx = j*1024 + k
  if (idx >= 512 * 1024) return;
  int k = idx & 1023;
  int j = idx >> 10;
  float v = (k < 512) ? w0[k * 512 + j] : w1[(k - 512) * 512 + j];
  wbT[idx] = f2bf(v);
}

// ---------------- histogram of destination rows (NT int4 reads) ----------------
__global__ __launch_bounds__(256) void histogram(const int* __restrict__ r0,
                                                 const int* __restrict__ r1,
                                                 int* __restrict__ c0,
                                                 int* __restrict__ c1) {
  const int nq = N_EDGES / 4;
  int stride = gridDim.x * blockDim.x;
  for (int i = blockIdx.x * blockDim.x + threadIdx.x; i < 2 * nq; i += stride) {
    if (i < nq) {
      i32x4 r = __builtin_nontemporal_load((const i32x4*)r0 + i);
      atomicAdd(&c0[r[0]], 1); atomicAdd(&c0[r[1]], 1);
      atomicAdd(&c0[r[2]], 1); atomicAdd(&c0[r[3]], 1);
    } else {
      i32x4 r = __builtin_nontemporal_load((const i32x4*)r1 + (i - nq));
      atomicAdd(&c1[r[0]], 1); atomicAdd(&c1[r[1]], 1);
      atomicAdd(&c1[r[2]], 1); atomicAdd(&c1[r[3]], 1);
    }
  }
}

// ---------------- exclusive scan, shuffle-based (one block per support) ----------------
__global__ __launch_bounds__(1024) void scan2(const int* __restrict__ cnt0,
                                              const int* __restrict__ cnt1,
                                              int* __restrict__ rp0, int* __restrict__ rp1,
                                              int* __restrict__ cur0, int* __restrict__ cur1) {
  __shared__ int wsum[16];
  __shared__ int stot;
  const int* cnt = (blockIdx.x == 0) ? cnt0 : cnt1;
  int* rp  = (blockIdx.x == 0) ? rp0  : rp1;
  int* cur = (blockIdx.x == 0) ? cur0 : cur1;
  const int t = threadIdx.x;
  const int lane = t & 63;
  const int wave = t >> 6;
  int carry = 0;
  for (int base = 0; base < N_NODES; base += 4096) {
    int idx = base + t * 4;
    int c0 = 0, c1 = 0, c2 = 0, c3 = 0;
    if (idx + 3 < N_NODES) {
      int4 c = *(const int4*)(cnt + idx);
      c0 = c.x; c1 = c.y; c2 = c.z; c3 = c.w;
    } else {
      if (idx     < N_NODES) c0 = cnt[idx];
      if (idx + 1 < N_NODES) c1 = cnt[idx + 1];
      if (idx + 2 < N_NODES) c2 = cnt[idx + 2];
      if (idx + 3 < N_NODES) c3 = cnt[idx + 3];
    }
    int s0 = c0, s01 = s0 + c1, s012 = s01 + c2, tsum = s012 + c3;
    int incl = tsum;
    #pragma unroll
    for (int off = 1; off < 64; off <<= 1) {
      int v = __shfl_up(incl, off, 64);
      if (lane >= off) incl += v;
    }
    if (lane == 63) wsum[wave] = incl;
    __syncthreads();
    if (wave == 0) {
      int v = (lane < 16) ? wsum[lane] : 0;
      int winc = v;
      #pragma unroll
      for (int off = 1; off < 16; off <<= 1) {
        int u = __shfl_up(winc, off, 64);
        if (lane >= off) winc += u;
      }
      if (lane < 16) wsum[lane] = winc - v;   // exclusive
      if (lane == 15) stot = winc;
    }
    __syncthreads();
    int ebase = carry + wsum[wave] + (incl - tsum);
    if (idx     < N_NODES) { rp[idx]     = ebase;        cur[idx]     = ebase; }
    if (idx + 1 < N_NODES) { rp[idx + 1] = ebase + s0;   cur[idx + 1] = ebase + s0; }
    if (idx + 2 < N_NODES) { rp[idx + 2] = ebase + s01;  cur[idx + 2] = ebase + s01; }
    if (idx + 3 < N_NODES) { rp[idx + 3] = ebase + s012; cur[idx + 3] = ebase + s012; }
    carry += stot;
    __syncthreads();
  }
  if (t == 0) rp[N_NODES] = carry;
}

// ---------------- CSR fill: packed (col, val) int2; NT vector reads ----------------
__global__ __launch_bounds__(256) void fill_csr(const int* __restrict__ r0, const int* __restrict__ co0, const float* __restrict__ v0,
                                                const int* __restrict__ r1, const int* __restrict__ co1, const float* __restrict__ v1,
                                                int* __restrict__ cur0, int* __restrict__ cur1,
                                                int2* __restrict__ e0, int2* __restrict__ e1) {
  const int nq = N_EDGES / 4;
  int stride = gridDim.x * blockDim.x;
  for (int i = blockIdx.x * blockDim.x + threadIdx.x; i < 2 * nq; i += stride) {
    if (i < nq) {
      i32x4 r = __builtin_nontemporal_load((const i32x4*)r0 + i);
      i32x4 c = __builtin_nontemporal_load((const i32x4*)co0 + i);
      f32x4 v = __builtin_nontemporal_load((const f32x4*)v0 + i);
      #pragma unroll
      for (int k = 0; k < 4; ++k) {
        int p = atomicAdd(&cur0[r[k]], 1);
        e0[p] = make_int2(c[k], __float_as_int(v[k]));
      }
    } else {
      int j = i - nq;
      i32x4 r = __builtin_nontemporal_load((const i32x4*)r1 + j);
      i32x4 c = __builtin_nontemporal_load((const i32x4*)co1 + j);
      f32x4 v = __builtin_nontemporal_load((const f32x4*)v1 + j);
      #pragma unroll
      for (int k = 0; k < 4; ++k) {
        int p = atomicAdd(&cur1[r[k]], 1);
        e1[p] = make_int2(c[k], __float_as_int(v[k]));
      }
    }
  }
}

// ---------------- SpMM on x: s[n][0:512] = A0 xb, s[n][512:1024] = A1 xb ----------------
// Block = 4 waves; each wave gathers whole 512-col rows (8 cols/lane), 4 edges in flight.
__global__ __launch_bounds__(256) void spmm_s(const unsigned short* __restrict__ xb,
    const int* __restrict__ rp0, const int2* __restrict__ e0,
    const int* __restrict__ rp1, const int2* __restrict__ e1,
    unsigned short* __restrict__ s) {
  __shared__ float red[4][576];   // 9-float stride per 8-elem lane group: conflict-free
  const int n = blockIdx.x;
  const int t = threadIdx.x;
  const int lane = t & 63;
  const int wave = __builtin_amdgcn_readfirstlane(t >> 6);
  const int c0 = lane * 8;

  float a0[8] = {}, a1[8] = {};

  #pragma unroll
  for (int sup = 0; sup < 2; ++sup) {
    const int* rp = sup ? rp1 : rp0;
    const int2* e = sup ? e1 : e0;
    float* acc = sup ? a1 : a0;
    const int beg = rp[n], end = rp[n + 1];
    int p = beg + wave;
    for (; p + 12 < end; p += 16) {
      i32x2 eA = __builtin_nontemporal_load((const i32x2*)(e + p));
      i32x2 eB = __builtin_nontemporal_load((const i32x2*)(e + p + 4));
      i32x2 eC = __builtin_nontemporal_load((const i32x2*)(e + p + 8));
      i32x2 eD = __builtin_nontemporal_load((const i32x2*)(e + p + 12));
      u16x8 rA = *(const u16x8*)(xb + (size_t)eA[0] * D + c0);
      u16x8 rB = *(const u16x8*)(xb + (size_t)eB[0] * D + c0);
      u16x8 rC = *(const u16x8*)(xb + (size_t)eC[0] * D + c0);
      u16x8 rD = *(const u16x8*)(xb + (size_t)eD[0] * D + c0);
      float vA = __int_as_float(eA[1]), vB = __int_as_float(eB[1]);
      float vC = __int_as_float(eC[1]), vD = __int_as_float(eD[1]);
      #pragma unroll
      for (int i = 0; i < 8; ++i) {
        acc[i] += vA * __uint_as_float(((unsigned)rA[i]) << 16);
        acc[i] += vB * __uint_as_float(((unsigned)rB[i]) << 16);
        acc[i] += vC * __uint_as_float(((unsigned)rC[i]) << 16);
        acc[i] += vD * __uint_as_float(((unsigned)rD[i]) << 16);
      }
    }
    for (; p < end; p += 4) {
      i32x2 eA = __builtin_nontemporal_load((const i32x2*)(e + p));
      u16x8 rA = *(const u16x8*)(xb + (size_t)eA[0] * D + c0);
      float vA = __int_as_float(eA[1]);
      #pragma unroll
      for (int i = 0; i < 8; ++i)
        acc[i] += vA * __uint_as_float(((unsigned)rA[i]) << 16);
    }
  }

  // reduce across waves; write bf16 s row with NT stores (keep L3 for xb)
  #pragma unroll
  for (int i = 0; i < 8; ++i) red[wave][lane * 9 + i] = a0[i];
  __syncthreads();
  {
    int cc = 2 * t;
    int ph = (cc >> 3) * 9 + (cc & 7);
    float x0 = red[0][ph] + red[1][ph] + red[2][ph] + red[3][ph];
    float x1 = red[0][ph + 1] + red[1][ph + 1] + red[2][ph + 1] + red[3][ph + 1];
    unsigned u = (unsigned)f2bf(x0) | ((unsigned)f2bf(x1) << 16);
    __builtin_nontemporal_store(u, (unsigned*)(s + (size_t)n * 1024 + cc));
  }
  __syncthreads();
  #pragma unroll
  for (int i = 0; i < 8; ++i) red[wave][lane * 9 + i] = a1[i];
  __syncthreads();
  {
    int cc = 2 * t;
    int ph = (cc >> 3) * 9 + (cc & 7);
    float x0 = red[0][ph] + red[1][ph] + red[2][ph] + red[3][ph];
    float x1 = red[0][ph + 1] + red[1][ph + 1] + red[2][ph + 1] + red[3][ph + 1];
    unsigned u = (unsigned)f2bf(x0) | ((unsigned)f2bf(x1) << 16);
    __builtin_nontemporal_store(u, (unsigned*)(s + (size_t)n * 1024 + 512 + cc));
  }
}

// ---------------- GEMM: out = relu( s[MPAD][1024] @ Wcat[1024][512] + b ), 2-phase dbuf ----------------
#define BM 128
#define BN 128
#define BK 32

__global__ __launch_bounds__(256) void gemm_out(const unsigned short* __restrict__ s,
                                                const unsigned short* __restrict__ wbT,
                                                const float* __restrict__ bias,
                                                float* __restrict__ out) {
  __shared__ __align__(16) unsigned short As[2][BM * BK];
  __shared__ __align__(16) unsigned short Bs[2][BN * BK];
  const int t = threadIdx.x;
  const int lane = t & 63;
  const int wave = t >> 6;
  const int wm = wave >> 1, wn = wave & 1;
  const int lr = lane & 15;
  const int lk = (lane >> 4) * 8;
  const int m0 = blockIdx.y * BM;
  const int n0 = blockIdx.x * BN;

  f32x4 acc[4][4] = {};
  const int NT = 1024 / BK;   // 32 K-steps

  auto STAGE = [&](int buf, int kt) {
    #pragma unroll
    for (int i = 0; i < 2; ++i) {
      int ch = i * 256 + t;          // 16B chunk index, 512 per tile
      int row = ch >> 2;
      int ke = (ch & 3) * 8;
      const unsigned short* ga = s + (size_t)(m0 + row) * 1024 + kt * BK + ke;
      __builtin_amdgcn_global_load_lds(
          (const __attribute__((address_space(1))) unsigned int*)ga,
          (__attribute__((address_space(3))) unsigned int*)(&As[buf][ch * 8]), 16, 0, 0);
      const unsigned short* gb = wbT + (size_t)(n0 + row) * 1024 + kt * BK + ke;
      __builtin_amdgcn_global_load_lds(
          (const __attribute__((address_space(1))) unsigned int*)gb,
          (__attribute__((address_space(3))) unsigned int*)(&Bs[buf][ch * 8]), 16, 0, 0);
    }
  };

  STAGE(0, 0);
  __syncthreads();   // drain vmcnt -> buf0 visible to all waves

  for (int kt = 0; kt < NT; ++kt) {
    const int cur = kt & 1;
    if (kt + 1 < NT) STAGE(cur ^ 1, kt + 1);   // prefetch overlaps this tile's compute

    bf16x8 a[4], b[4];
    #pragma unroll
    for (int i = 0; i < 4; ++i)
      a[i] = *(const bf16x8*)&As[cur][(wm * 64 + i * 16 + lr) * BK + lk];
    #pragma unroll
    for (int j = 0; j < 4; ++j)
      b[j] = *(const bf16x8*)&Bs[cur][(wn * 64 + j * 16 + lr) * BK + lk];
    #pragma unroll
    for (int i = 0; i < 4; ++i)
      #pragma unroll
      for (int j = 0; j < 4; ++j)
        acc[i][j] = __builtin_amdgcn_mfma_f32_16x16x32_bf16(a[i], b[j], acc[i][j], 0, 0, 0);
    __syncthreads();   // drains prefetch vmcnt + barrier: next buf ready
  }

  float bj[4];
  #pragma unroll
  for (int j = 0; j < 4; ++j) bj[j] = bias[n0 + wn * 64 + j * 16 + lr];

  const int orow = (lane >> 4) * 4;
  #pragma unroll
  for (int i = 0; i < 4; ++i) {
    #pragma unroll
    for (int j = 0; j < 4; ++j) {
      #pragma unroll
      for (int r = 0; r < 4; ++r) {
        int row = m0 + wm * 64 + i * 16 + orow + r;
        if (row < N_NODES) {
          int col = n0 + wn * 64 + j * 16 + lr;
          __builtin_nontemporal_store(fmaxf(acc[i][j][r] + bj[j], 0.f),
                                      out + (size_t)row * 512 + col);
        }
      }
    }
  }
}

// ---------------- launch ----------------
extern "C" void kernel_launch(void* const* d_in, const int* in_sizes, int n_in,
                              void* d_out, int out_size, void* d_ws, size_t ws_size,
                              hipStream_t stream) {
  const float* x     = (const float*)d_in[0];
  const float* w0    = (const float*)d_in[1];
  const float* w1    = (const float*)d_in[2];
  const float* bias  = (const float*)d_in[3];
  const float* vals0 = (const float*)d_in[4];
  const float* vals1 = (const float*)d_in[5];
  const int*   rows0 = (const int*)d_in[6];
  const int*   cols0 = (const int*)d_in[7];
  const int*   rows1 = (const int*)d_in[8];
  const int*   cols1 = (const int*)d_in[9];
  float* out = (float*)d_out;

  char* ws = (char*)d_ws;
  size_t off = 0;
  auto alloc = [&](size_t bytes) -> char* {
    char* p = ws + off;
    off += (bytes + 255) & ~(size_t)255;
    return p;
  };
  unsigned short* xb  = (unsigned short*)alloc((size_t)N_NODES * D * 2);   // 51.2 MB
  unsigned short* wbT = (unsigned short*)alloc((size_t)512 * 1024 * 2);    // 1 MB
  unsigned short* s   = (unsigned short*)alloc((size_t)MPAD * 1024 * 2);   // 102.5 MB
  int* rp0  = (int*)alloc((N_NODES + 1) * sizeof(int));
  int* rp1  = (int*)alloc((N_NODES + 1) * sizeof(int));
  int* cur0 = (int*)alloc(N_NODES * sizeof(int));
  int* cur1 = (int*)alloc(N_NODES * sizeof(int));
  int* cnt  = (int*)alloc(2 * N_NODES * sizeof(int));
  int2* e0  = (int2*)alloc((size_t)N_EDGES * sizeof(int2));                // 12.8 MB
  int2* e1  = (int2*)alloc((size_t)N_EDGES * sizeof(int2));                // 12.8 MB

  hipMemsetAsync(cnt, 0, 2 * N_NODES * sizeof(int), stream);
  hipMemsetAsync(s + (size_t)N_NODES * 1024, 0, (size_t)(MPAD - N_NODES) * 1024 * 2, stream);

  convert_x<<<dim3((unsigned)((size_t)N_NODES * D / 8 / 256)), 256, 0, stream>>>(x, xb);
  convert_w<<<dim3(512 * 1024 / 256), 256, 0, stream>>>(w0, w1, wbT);
  histogram<<<2048, 256, 0, stream>>>(rows0, rows1, cnt, cnt + N_NODES);
  scan2<<<2, 1024, 0, stream>>>(cnt, cnt + N_NODES, rp0, rp1, cur0, cur1);
  fill_csr<<<2048, 256, 0, stream>>>(rows0, cols0, vals0, rows1, cols1, vals1,
                                     cur0, cur1, e0, e1);
  spmm_s<<<N_NODES, 256, 0, stream>>>(xb, rp0, e0, rp1, e1, s);
  gemm_out<<<dim3(512 / BN, MPAD / BM), 256, 0, stream>>>(s, wbT, bias, out);
}